// Round 1
// 1778.916 us; speedup vs baseline: 1.0404x; 1.0404x over previous
//
#include <hip/hip_runtime.h>
#include <hip/hip_fp16.h>

// LSTM Autoencoder: B=256, T=128, I=512, H=1024, E=256
// Round-3: DATAFLOW handoff. Per-step-unique h buffers pre-poisoned with fp16
// NaN (0x7C7C); h = sigmoid*tanh can never be NaN, so consumers spin directly
// on the data chunks with relaxed agent (sc0+sc1) loads. Removes the entire
// flag protocol from the critical path: no producer vmcnt(0) drain, no flag
// store/poll round-trip. Producers fire-and-forget; sync cost = one-way
// store-to-LLC latency. Stores are 4B-atomic pairs -> check all 4 dwords of
// each 16B chunk. Falls back to the verified round-2 flag protocol if ws is
// too small for the 129-slot buffers.

#define B_ 256
#define T_ 128
#define I_ 512
#define H_ 1024
#define E_ 256

#define ENC_STEP 262144   // fp16 elems per encoder h slot (256x1024)
#define DEC_STEP 131072   // fp16 elems per decoder h slot (256x512)
#define SENT32 0x7C7C7C7Cu   // two fp16 NaNs; unreachable by real h pairs

typedef _Float16 half8 __attribute__((ext_vector_type(8)));
typedef float floatx4 __attribute__((ext_vector_type(4)));

__device__ __forceinline__ float sigmoidf_(float x) { return 1.0f / (1.0f + __expf(-x)); }
__device__ __forceinline__ float tanhf_(float x) {
    x = fminf(fmaxf(x, -15.0f), 15.0f);
    float e = __expf(2.0f * x);
    return (e - 1.0f) / (e + 1.0f);
}

union HU { unsigned long long u[2]; half8 h; };

// coherent 16B load as 2x u64 relaxed-agent atomics (global_load_dwordx2 sc0 sc1)
__device__ __forceinline__ void ld_chunk(const _Float16* p, HU& v) {
    const unsigned long long* q = (const unsigned long long*)p;
    v.u[0] = __hip_atomic_load(q,     __ATOMIC_RELAXED, __HIP_MEMORY_SCOPE_AGENT);
    v.u[1] = __hip_atomic_load(q + 1, __ATOMIC_RELAXED, __HIP_MEMORY_SCOPE_AGENT);
}
// a chunk is ready iff none of its 4 (atomically-written) dwords is sentinel
__device__ __forceinline__ int chunk_ok(const HU& v) {
    unsigned a = (unsigned)v.u[0], b = (unsigned)(v.u[0] >> 32);
    unsigned c = (unsigned)v.u[1], d = (unsigned)(v.u[1] >> 32);
    return (int)((a != SENT32) & (b != SENT32) & (c != SENT32) & (d != SENT32));
}
template <int STRIDE>
__device__ __forceinline__ void load_grp(const _Float16* base, HU v[4]) {
#pragma unroll
    for (int m = 0; m < 4; ++m) ld_chunk(base + (size_t)m * STRIDE, v[m]);
}
template <int STRIDE>
__device__ __forceinline__ void fix_grp(const _Float16* base, HU v[4]) {
    // per-lane spin; first check is free (uses the already-issued loads)
    while (!(chunk_ok(v[0]) & chunk_ok(v[1]) & chunk_ok(v[2]) & chunk_ok(v[3]))) {
        __builtin_amdgcn_s_sleep(1);
        load_grp<STRIDE>(base, v);
    }
}

// legacy helpers (fallback path + stores shared by both paths)
__device__ __forceinline__ half8 ldg_h8_sc1(const _Float16* p) {
    HU v; ld_chunk(p, v); return v.h;
}
__device__ __forceinline__ void stg_h2_sc1(_Float16* p, float a, float b) {
    union { _Float16 h[2]; unsigned int u; } v;
    v.h[0] = (_Float16)a; v.h[1] = (_Float16)b;
    __hip_atomic_store((unsigned int*)p, v.u, __ATOMIC_RELAXED, __HIP_MEMORY_SCOPE_AGENT);
}
__device__ __forceinline__ void wait_vm0() {
    asm volatile("s_waitcnt vmcnt(0)" ::: "memory");
}
__device__ __forceinline__ void poll_rg(int* flags, int rgbase, int lane, int target) {
    while (__hip_atomic_load(&flags[rgbase + lane], __ATOMIC_RELAXED, __HIP_MEMORY_SCOPE_AGENT) < target)
        __builtin_amdgcn_s_sleep(1);
    asm volatile("" ::: "memory");
}

// ---------------- x -> MFMA A-fragment layout (once) ----------------
__global__ void shuffle_x_kernel(const float* __restrict__ x, _Float16* __restrict__ xf) {
    const int gg   = blockIdx.x * 256 + threadIdx.x;
    const int tile = gg >> 6;
    const int lane = gg & 63;
    const int t  = tile >> 8;
    const int rt = (tile >> 4) & 15;
    const int kc = tile & 15;
    const int b  = rt * 16 + (lane & 15);
    const int j0 = kc * 32 + ((lane >> 4) << 3);
    const float* src = x + ((size_t)b * T_ + t) * I_ + j0;
    float4 f0 = *(const float4*)src;
    float4 f1 = *(const float4*)(src + 4);
    half8 h = { (_Float16)f0.x, (_Float16)f0.y, (_Float16)f0.z, (_Float16)f0.w,
                (_Float16)f1.x, (_Float16)f1.y, (_Float16)f1.z, (_Float16)f1.w };
    *(half8*)(xf + (size_t)tile * 512 + lane * 8) = h;
}

// ---------------- small fp32 GEMM ----------------
__global__ __launch_bounds__(256) void small_gemm_kernel(
    const float* __restrict__ A, int lda,
    const float* __restrict__ W, int ldw,
    const float* __restrict__ b1, const float* __restrict__ b2,
    float* __restrict__ out, int N, int K, int relu)
{
    __shared__ float sA2[32][33];
    __shared__ float sW2[32][33];
    int tid = threadIdx.x;
    int tx = tid & 15, ty = tid >> 4;
    int m0 = blockIdx.y * 32, n0 = blockIdx.x * 32;
    float acc[2][2] = {};
    for (int k0 = 0; k0 < K; k0 += 32) {
        __syncthreads();
#pragma unroll
        for (int i = 0; i < 4; ++i) {
            int e = tid + i * 256;
            int r = e >> 5, c = e & 31;
            sA2[r][c] = A[(size_t)(m0 + r) * lda + k0 + c];
            sW2[r][c] = W[(size_t)(n0 + r) * ldw + k0 + c];
        }
        __syncthreads();
#pragma unroll
        for (int k = 0; k < 32; ++k) {
            float a0 = sA2[ty * 2][k], a1 = sA2[ty * 2 + 1][k];
            float w0 = sW2[tx * 2][k], w1 = sW2[tx * 2 + 1][k];
            acc[0][0] += a0 * w0; acc[0][1] += a0 * w1;
            acc[1][0] += a1 * w0; acc[1][1] += a1 * w1;
        }
    }
#pragma unroll
    for (int i = 0; i < 2; ++i)
#pragma unroll
        for (int j = 0; j < 2; ++j) {
            int m = m0 + ty * 2 + i, n = n0 + tx * 2 + j;
            float v = acc[i][j] + b1[n] + (b2 ? b2[n] : 0.0f);
            if (relu) v = fmaxf(v, 0.0f);
            out[(size_t)m * N + n] = v;
        }
}

// ================= PRIMARY: dataflow encoder =================
// grid 256 = 4 row-groups x 64 col-blocks; per-step-unique h slots.
__global__ __launch_bounds__(256, 1) void enc_df(
    const _Float16* __restrict__ xf,
    const float* __restrict__ Wih, const float* __restrict__ Whh,
    const float* __restrict__ bih, const float* __restrict__ bhh,
    _Float16* __restrict__ hbuf, float* __restrict__ c_out)
{
    const int tid  = threadIdx.x;
    const int wave = tid >> 6, lane = tid & 63;
    const int q = lane >> 4, n15 = lane & 15;
    const int blk = blockIdx.x;
    const int rg = blk >> 6, cc = blk & 63;

    // weights -> VGPRs (192 regs/lane)
    half8 bw[4][12];
#pragma unroll
    for (int g = 0; g < 4; ++g) {
        const int jc = g * H_ + cc * 16 + n15;
#pragma unroll
        for (int kc = 0; kc < 12; ++kc) {
            const int k = (4 * kc + wave) * 32 + q * 8;
            const float* src = (k < I_) ? (Wih + (size_t)jc * I_ + k)
                                        : (Whh + (size_t)jc * H_ + (k - I_));
            float4 f0 = *(const float4*)src;
            float4 f1 = *(const float4*)(src + 4);
            bw[g][kc] = half8{(_Float16)f0.x, (_Float16)f0.y, (_Float16)f0.z, (_Float16)f0.w,
                              (_Float16)f1.x, (_Float16)f1.y, (_Float16)f1.z, (_Float16)f1.w};
        }
    }

    const int hcp = tid & 7;
    const int rT  = tid >> 3;
    float breg[4][2];
#pragma unroll
    for (int g = 0; g < 4; ++g)
#pragma unroll
        for (int e = 0; e < 2; ++e) {
            const int j = g * H_ + cc * 16 + 2 * hcp + e;
            breg[g][e] = bih[j] + bhh[j];
        }
    float creg[2][2] = {{0.f, 0.f}, {0.f, 0.f}};

    __shared__ float preT[4][64][35];
    const size_t laneoff = (size_t)lane * 8;

    for (int s = 0; s < T_; ++s) {
        const _Float16* __restrict__ hcur = hbuf + (size_t)s * ENC_STEP;
        _Float16* __restrict__ hnxt = hbuf + (size_t)(s + 1) * ENC_STEP;

        floatx4 acc[4][4];
#pragma unroll
        for (int m = 0; m < 4; ++m)
#pragma unroll
            for (int n = 0; n < 4; ++n) acc[m][n] = floatx4{0.f, 0.f, 0.f, 0.f};

        // ---- x phase (independent of h): hides peer production lag
        half8 X[4][4];
#pragma unroll
        for (int kc = 0; kc < 4; ++kc)
#pragma unroll
            for (int m = 0; m < 4; ++m)
                X[kc][m] = *(const half8*)(xf + (((size_t)s * 16 + rg * 4 + m) * 16
                                                + (4 * kc + wave)) * 512 + laneoff);
#pragma unroll
        for (int kc = 0; kc < 4; ++kc)
#pragma unroll
            for (int n = 0; n < 4; ++n)
#pragma unroll
                for (int m = 0; m < 4; ++m)
                    acc[m][n] = __builtin_amdgcn_mfma_f32_16x16x32_f16(
                        X[kc][m], bw[n][kc], acc[m][n], 0, 0, 0);

        // ---- h phase: optimistic loads, sentinel-verified right before use
        HU Hb[4][4];
#pragma unroll
        for (int kc = 4; kc < 8; ++kc)
            load_grp<32 * 512>(hcur + ((size_t)(rg * 4) * 32 + (4 * kc + wave - 16)) * 512
                                    + laneoff, Hb[kc - 4]);
#pragma unroll
        for (int kc = 4; kc < 12; ++kc) {
            const int sl = kc & 3;
            fix_grp<32 * 512>(hcur + ((size_t)(rg * 4) * 32 + (4 * kc + wave - 16)) * 512
                                   + laneoff, Hb[sl]);
#pragma unroll
            for (int n = 0; n < 4; ++n)
#pragma unroll
                for (int m = 0; m < 4; ++m)
                    acc[m][n] = __builtin_amdgcn_mfma_f32_16x16x32_f16(
                        Hb[sl][m].h, bw[n][kc], acc[m][n], 0, 0, 0);
            if (kc < 8)
                load_grp<32 * 512>(hcur + ((size_t)(rg * 4) * 32 + (4 * (kc + 4) + wave - 16)) * 512
                                        + laneoff, Hb[sl]);
        }

        // ---- epilogue: 2 phases (rows 0..31, 32..63)
#pragma unroll
        for (int p = 0; p < 2; ++p) {
            if (p) __syncthreads();
#pragma unroll
            for (int m = 0; m < 2; ++m)
#pragma unroll
                for (int n = 0; n < 4; ++n)
#pragma unroll
                    for (int r = 0; r < 4; ++r)
                        preT[wave][n * 16 + n15][m * 16 + q * 4 + r] = acc[p * 2 + m][n][r];
            __syncthreads();
            float pg[4][2];
#pragma unroll
            for (int g = 0; g < 4; ++g)
#pragma unroll
                for (int e = 0; e < 2; ++e) {
                    const int col = g * 16 + 2 * hcp + e;
                    pg[g][e] = preT[0][col][rT] + preT[1][col][rT]
                             + preT[2][col][rT] + preT[3][col][rT] + breg[g][e];
                }
            float hv[2];
#pragma unroll
            for (int e = 0; e < 2; ++e) {
                const float ig = sigmoidf_(pg[0][e]);
                const float fg = sigmoidf_(pg[1][e]);
                const float gg = tanhf_(pg[2][e]);
                const float og = sigmoidf_(pg[3][e]);
                const float c  = fg * creg[p][e] + ig * gg;
                creg[p][e] = c;
                hv[e] = og * tanhf_(c);
            }
            const int row = p * 32 + rT;
            const int j   = cc * 16 + 2 * hcp;
            const int kch = j >> 5, j5 = j & 31;
            const int lt  = (row & 15) | ((j5 >> 3) << 4);
            stg_h2_sc1(hnxt + ((size_t)(rg * 4 + (row >> 4)) * 32 + kch) * 512
                            + lt * 8 + (j5 & 7), hv[0], hv[1]);
        }
        // fire-and-forget: no drain, no flag. Sync protects preT across steps.
        __syncthreads();
    }

#pragma unroll
    for (int p = 0; p < 2; ++p)
        *(float2*)(c_out + (size_t)(rg * 64 + p * 32 + rT) * H_ + cc * 16 + 2 * hcp)
            = float2{creg[p][0], creg[p][1]};
}

// ================= PRIMARY: dataflow decoder =================
__global__ __launch_bounds__(256, 1) void dec_df(
    const float* __restrict__ dWih, const float* __restrict__ dWhh,
    const float* __restrict__ fixedb,
    _Float16* __restrict__ hbuf, float* __restrict__ out)
{
    const int tid  = threadIdx.x;
    const int wave = tid >> 6, lane = tid & 63;
    const int q = lane >> 4, n15 = lane & 15;
    const int blk = blockIdx.x;
    const int rg = blk >> 6, cc = blk & 63;

    half8 bw[2][4];
#pragma unroll
    for (int n = 0; n < 2; ++n) {
        const int jc = (n * 2 + (n15 >> 3)) * I_ + cc * 8 + (n15 & 7);
#pragma unroll
        for (int kc = 0; kc < 4; ++kc) {
            const int k = wave * 128 + kc * 32 + q * 8;
            const float* s0 = dWih + (size_t)jc * (H_ + I_) + H_ + k;
            const float* s1 = dWhh + (size_t)jc * I_ + k;
            float4 a0 = *(const float4*)s0, a1 = *(const float4*)(s0 + 4);
            float4 b0 = *(const float4*)s1, b1 = *(const float4*)(s1 + 4);
            bw[n][kc] = half8{(_Float16)(a0.x + b0.x), (_Float16)(a0.y + b0.y),
                              (_Float16)(a0.z + b0.z), (_Float16)(a0.w + b0.w),
                              (_Float16)(a1.x + b1.x), (_Float16)(a1.y + b1.y),
                              (_Float16)(a1.z + b1.z), (_Float16)(a1.w + b1.w)};
        }
    }

    const int hcp = tid & 3;
    const int rT  = tid >> 2;
    const int brow = rg * 64 + rT;
    float fx[4][2];
#pragma unroll
    for (int g = 0; g < 4; ++g)
#pragma unroll
        for (int e = 0; e < 2; ++e)
            fx[g][e] = fixedb[(size_t)brow * (4 * I_) + g * I_ + cc * 8 + 2 * hcp + e];
    float creg2[2] = {0.f, 0.f};

    __shared__ float preT[4][32][67];
    const size_t laneoff = (size_t)lane * 8;

    for (int s = 0; s < T_; ++s) {
        const _Float16* __restrict__ hcur = hbuf + (size_t)s * DEC_STEP;
        _Float16* __restrict__ hnxt = hbuf + (size_t)(s + 1) * DEC_STEP;

        HU Hb[4][4];
#pragma unroll
        for (int kc = 0; kc < 4; ++kc)
            load_grp<16 * 512>(hcur + ((size_t)(rg * 4) * 16 + (wave * 4 + kc)) * 512
                                    + laneoff, Hb[kc]);

        floatx4 acc[4][2];
#pragma unroll
        for (int m = 0; m < 4; ++m)
#pragma unroll
            for (int n = 0; n < 2; ++n) acc[m][n] = floatx4{0.f, 0.f, 0.f, 0.f};
#pragma unroll
        for (int kc = 0; kc < 4; ++kc) {
            fix_grp<16 * 512>(hcur + ((size_t)(rg * 4) * 16 + (wave * 4 + kc)) * 512
                                   + laneoff, Hb[kc]);
#pragma unroll
            for (int n = 0; n < 2; ++n)
#pragma unroll
                for (int m = 0; m < 4; ++m)
                    acc[m][n] = __builtin_amdgcn_mfma_f32_16x16x32_f16(
                        Hb[kc][m].h, bw[n][kc], acc[m][n], 0, 0, 0);
        }

#pragma unroll
        for (int p = 0; p < 2; ++p) {
            if (p) __syncthreads();
#pragma unroll
            for (int m = 0; m < 2; ++m)
#pragma unroll
                for (int n = 0; n < 2; ++n)
#pragma unroll
                    for (int r = 0; r < 4; ++r)
                        preT[wave][n * 16 + n15][m * 16 + q * 4 + r] = acc[p * 2 + m][n][r];
            __syncthreads();
            if ((rT >> 5) == p) {
                const int rl = rT & 31;
                float pg[4][2];
#pragma unroll
                for (int g = 0; g < 4; ++g)
#pragma unroll
                    for (int e = 0; e < 2; ++e) {
                        const int col = (g >> 1) * 16 + (g & 1) * 8 + 2 * hcp + e;
                        pg[g][e] = preT[0][col][rl] + preT[1][col][rl]
                                 + preT[2][col][rl] + preT[3][col][rl] + fx[g][e];
                    }
                float hv[2];
#pragma unroll
                for (int e = 0; e < 2; ++e) {
                    const float ig = sigmoidf_(pg[0][e]);
                    const float fg = sigmoidf_(pg[1][e]);
                    const float gg = tanhf_(pg[2][e]);
                    const float og = sigmoidf_(pg[3][e]);
                    const float c  = fg * creg2[e] + ig * gg;
                    creg2[e] = c;
                    hv[e] = og * tanhf_(c);
                }
                *(float2*)(out + ((size_t)brow * T_ + (T_ - 1 - s)) * I_ + cc * 8 + 2 * hcp)
                    = float2{hv[0], hv[1]};
                const int j = cc * 8 + 2 * hcp;
                const int kch = j >> 5, j5 = j & 31;
                const int lt  = (rT & 15) | ((j5 >> 3) << 4);
                stg_h2_sc1(hnxt + ((size_t)(rg * 4 + (rT >> 4)) * 16 + kch) * 512
                                + lt * 8 + (j5 & 7), hv[0], hv[1]);
            }
        }
        __syncthreads();
    }
}

// ================= FALLBACK: round-2 verified flag protocol =================
__global__ __launch_bounds__(256, 1) void enc_persist(
    const _Float16* __restrict__ xf,
    const float* __restrict__ Wih, const float* __restrict__ Whh,
    const float* __restrict__ bih, const float* __restrict__ bhh,
    _Float16* __restrict__ hbuf, float* __restrict__ c_out, int* __restrict__ flags)
{
    const int tid  = threadIdx.x;
    const int wave = tid >> 6, lane = tid & 63;
    const int q = lane >> 4, n15 = lane & 15;
    const int blk = blockIdx.x;
    const int rg = blk >> 6, cc = blk & 63;

    half8 bw[4][12];
#pragma unroll
    for (int g = 0; g < 4; ++g) {
        const int jc = g * H_ + cc * 16 + n15;
#pragma unroll
        for (int kc = 0; kc < 12; ++kc) {
            const int k = (4 * kc + wave) * 32 + q * 8;
            const float* src = (k < I_) ? (Wih + (size_t)jc * I_ + k)
                                        : (Whh + (size_t)jc * H_ + (k - I_));
            float4 f0 = *(const float4*)src;
            float4 f1 = *(const float4*)(src + 4);
            bw[g][kc] = half8{(_Float16)f0.x, (_Float16)f0.y, (_Float16)f0.z, (_Float16)f0.w,
                              (_Float16)f1.x, (_Float16)f1.y, (_Float16)f1.z, (_Float16)f1.w};
        }
    }

    const int hcp = tid & 7;
    const int rT  = tid >> 3;
    float breg[4][2];
#pragma unroll
    for (int g = 0; g < 4; ++g)
#pragma unroll
        for (int e = 0; e < 2; ++e) {
            const int j = g * H_ + cc * 16 + 2 * hcp + e;
            breg[g][e] = bih[j] + bhh[j];
        }
    float creg[2][2] = {{0.f, 0.f}, {0.f, 0.f}};

    __shared__ float preT[4][64][35];
    const size_t laneoff = (size_t)lane * 8;

    for (int s = 0; s < T_; ++s) {
        const _Float16* __restrict__ hcur = hbuf + (size_t)(s & 1) * 262144;
        _Float16* __restrict__ hnxt = hbuf + (size_t)((s + 1) & 1) * 262144;

        floatx4 acc[4][4];
#pragma unroll
        for (int m = 0; m < 4; ++m)
#pragma unroll
            for (int n = 0; n < 4; ++n) acc[m][n] = floatx4{0.f, 0.f, 0.f, 0.f};

        half8 X[4][4];
#pragma unroll
        for (int kc = 0; kc < 4; ++kc)
#pragma unroll
            for (int m = 0; m < 4; ++m)
                X[kc][m] = *(const half8*)(xf + (((size_t)s * 16 + rg * 4 + m) * 16
                                                + (4 * kc + wave)) * 512 + laneoff);
#pragma unroll
        for (int kc = 0; kc < 4; ++kc)
#pragma unroll
            for (int n = 0; n < 4; ++n)
#pragma unroll
                for (int m = 0; m < 4; ++m)
                    acc[m][n] = __builtin_amdgcn_mfma_f32_16x16x32_f16(
                        X[kc][m], bw[n][kc], acc[m][n], 0, 0, 0);

        poll_rg(flags, rg * 64, lane, s);

        half8 Hb[4][4];
#pragma unroll
        for (int kc = 4; kc < 8; ++kc)
#pragma unroll
            for (int m = 0; m < 4; ++m)
                Hb[kc - 4][m] = ldg_h8_sc1(hcur + ((size_t)(rg * 4 + m) * 32
                                                   + (4 * kc + wave - 16)) * 512 + laneoff);
#pragma unroll
        for (int kc = 4; kc < 12; ++kc) {
            const int sl = kc & 3;
#pragma unroll
            for (int n = 0; n < 4; ++n)
#pragma unroll
                for (int m = 0; m < 4; ++m)
                    acc[m][n] = __builtin_amdgcn_mfma_f32_16x16x32_f16(
                        Hb[sl][m], bw[n][kc], acc[m][n], 0, 0, 0);
            if (kc < 8) {
#pragma unroll
                for (int m = 0; m < 4; ++m)
                    Hb[sl][m] = ldg_h8_sc1(hcur + ((size_t)(rg * 4 + m) * 32
                                                   + (4 * (kc + 4) + wave - 16)) * 512 + laneoff);
            }
        }

#pragma unroll
        for (int p = 0; p < 2; ++p) {
            if (p) __syncthreads();
#pragma unroll
            for (int m = 0; m < 2; ++m)
#pragma unroll
                for (int n = 0; n < 4; ++n)
#pragma unroll
                    for (int r = 0; r < 4; ++r)
                        preT[wave][n * 16 + n15][m * 16 + q * 4 + r] = acc[p * 2 + m][n][r];
            __syncthreads();
            float pg[4][2];
#pragma unroll
            for (int g = 0; g < 4; ++g)
#pragma unroll
                for (int e = 0; e < 2; ++e) {
                    const int col = g * 16 + 2 * hcp + e;
                    pg[g][e] = preT[0][col][rT] + preT[1][col][rT]
                             + preT[2][col][rT] + preT[3][col][rT] + breg[g][e];
                }
            float hv[2];
#pragma unroll
            for (int e = 0; e < 2; ++e) {
                const float ig = sigmoidf_(pg[0][e]);
                const float fg = sigmoidf_(pg[1][e]);
                const float gg = tanhf_(pg[2][e]);
                const float og = sigmoidf_(pg[3][e]);
                const float c  = fg * creg[p][e] + ig * gg;
                creg[p][e] = c;
                hv[e] = og * tanhf_(c);
            }
            const int row = p * 32 + rT;
            const int j   = cc * 16 + 2 * hcp;
            const int kch = j >> 5, j5 = j & 31;
            const int lt  = (row & 15) | ((j5 >> 3) << 4);
            stg_h2_sc1(hnxt + ((size_t)(rg * 4 + (row >> 4)) * 32 + kch) * 512
                            + lt * 8 + (j5 & 7), hv[0], hv[1]);
        }

        wait_vm0();
        __syncthreads();
        if (tid == 0)
            __hip_atomic_store(&flags[blk], s + 1, __ATOMIC_RELAXED, __HIP_MEMORY_SCOPE_AGENT);
    }

#pragma unroll
    for (int p = 0; p < 2; ++p)
        *(float2*)(c_out + (size_t)(rg * 64 + p * 32 + rT) * H_ + cc * 16 + 2 * hcp)
            = float2{creg[p][0], creg[p][1]};
}

__global__ __launch_bounds__(256, 1) void dec_persist(
    const float* __restrict__ dWih, const float* __restrict__ dWhh,
    const float* __restrict__ fixedb,
    _Float16* __restrict__ hbuf, float* __restrict__ out, int* __restrict__ flags)
{
    const int tid  = threadIdx.x;
    const int wave = tid >> 6, lane = tid & 63;
    const int q = lane >> 4, n15 = lane & 15;
    const int blk = blockIdx.x;
    const int rg = blk >> 6, cc = blk & 63;

    half8 bw[2][4];
#pragma unroll
    for (int n = 0; n < 2; ++n) {
        const int jc = (n * 2 + (n15 >> 3)) * I_ + cc * 8 + (n15 & 7);
#pragma unroll
        for (int kc = 0; kc < 4; ++kc) {
            const int k = wave * 128 + kc * 32 + q * 8;
            const float* s0 = dWih + (size_t)jc * (H_ + I_) + H_ + k;
            const float* s1 = dWhh + (size_t)jc * I_ + k;
            float4 a0 = *(const float4*)s0, a1 = *(const float4*)(s0 + 4);
            float4 b0 = *(const float4*)s1, b1 = *(const float4*)(s1 + 4);
            bw[n][kc] = half8{(_Float16)(a0.x + b0.x), (_Float16)(a0.y + b0.y),
                              (_Float16)(a0.z + b0.z), (_Float16)(a0.w + b0.w),
                              (_Float16)(a1.x + b1.x), (_Float16)(a1.y + b1.y),
                              (_Float16)(a1.z + b1.z), (_Float16)(a1.w + b1.w)};
        }
    }

    const int hcp = tid & 3;
    const int rT  = tid >> 2;
    const int brow = rg * 64 + rT;
    float fx[4][2];
#pragma unroll
    for (int g = 0; g < 4; ++g)
#pragma unroll
        for (int e = 0; e < 2; ++e)
            fx[g][e] = fixedb[(size_t)brow * (4 * I_) + g * I_ + cc * 8 + 2 * hcp + e];
    float creg2[2] = {0.f, 0.f};

    __shared__ float preT[4][32][67];
    const size_t laneoff = (size_t)lane * 8;

    for (int s = 0; s < T_; ++s) {
        const _Float16* __restrict__ hcur = hbuf + (size_t)(s & 1) * 131072;
        _Float16* __restrict__ hnxt = hbuf + (size_t)((s + 1) & 1) * 131072;

        poll_rg(flags, rg * 64, lane, s);

        half8 Hb[4][4];
#pragma unroll
        for (int kc = 0; kc < 4; ++kc)
#pragma unroll
            for (int m = 0; m < 4; ++m)
                Hb[kc][m] = ldg_h8_sc1(hcur + ((size_t)(rg * 4 + m) * 16
                                               + (wave * 4 + kc)) * 512 + laneoff);
        floatx4 acc[4][2];
#pragma unroll
        for (int m = 0; m < 4; ++m)
#pragma unroll
            for (int n = 0; n < 2; ++n) acc[m][n] = floatx4{0.f, 0.f, 0.f, 0.f};
#pragma unroll
        for (int kc = 0; kc < 4; ++kc)
#pragma unroll
            for (int n = 0; n < 2; ++n)
#pragma unroll
                for (int m = 0; m < 4; ++m)
                    acc[m][n] = __builtin_amdgcn_mfma_f32_16x16x32_f16(
                        Hb[kc][m], bw[n][kc], acc[m][n], 0, 0, 0);

#pragma unroll
        for (int p = 0; p < 2; ++p) {
            if (p) __syncthreads();
#pragma unroll
            for (int m = 0; m < 2; ++m)
#pragma unroll
                for (int n = 0; n < 2; ++n)
#pragma unroll
                    for (int r = 0; r < 4; ++r)
                        preT[wave][n * 16 + n15][m * 16 + q * 4 + r] = acc[p * 2 + m][n][r];
            __syncthreads();
            if ((rT >> 5) == p) {
                const int rl = rT & 31;
                float pg[4][2];
#pragma unroll
                for (int g = 0; g < 4; ++g)
#pragma unroll
                    for (int e = 0; e < 2; ++e) {
                        const int col = (g >> 1) * 16 + (g & 1) * 8 + 2 * hcp + e;
                        pg[g][e] = preT[0][col][rl] + preT[1][col][rl]
                                 + preT[2][col][rl] + preT[3][col][rl] + fx[g][e];
                    }
                float hv[2];
#pragma unroll
                for (int e = 0; e < 2; ++e) {
                    const float ig = sigmoidf_(pg[0][e]);
                    const float fg = sigmoidf_(pg[1][e]);
                    const float gg = tanhf_(pg[2][e]);
                    const float og = sigmoidf_(pg[3][e]);
                    const float c  = fg * creg2[e] + ig * gg;
                    creg2[e] = c;
                    hv[e] = og * tanhf_(c);
                }
                *(float2*)(out + ((size_t)brow * T_ + (T_ - 1 - s)) * I_ + cc * 8 + 2 * hcp)
                    = float2{hv[0], hv[1]};
                const int j = cc * 8 + 2 * hcp;
                const int kch = j >> 5, j5 = j & 31;
                const int lt  = (rT & 15) | ((j5 >> 3) << 4);
                stg_h2_sc1(hnxt + ((size_t)(rg * 4 + (rT >> 4)) * 16 + kch) * 512
                                + lt * 8 + (j5 & 7), hv[0], hv[1]);
            }
        }

        wait_vm0();
        __syncthreads();
        if (tid == 0)
            __hip_atomic_store(&flags[blk], s + 1, __ATOMIC_RELAXED, __HIP_MEMORY_SCOPE_AGENT);
    }
}

// ---------------- launch ----------------
extern "C" void kernel_launch(void* const* d_in, const int* in_sizes, int n_in,
                              void* d_out_v, int out_size, void* d_ws, size_t ws_size,
                              hipStream_t stream) {
    (void)in_sizes; (void)n_in; (void)out_size;
    const float* x    = (const float*)d_in[0];
    const float* eWih = (const float*)d_in[1];
    const float* eWhh = (const float*)d_in[2];
    const float* ebih = (const float*)d_in[3];
    const float* ebhh = (const float*)d_in[4];
    const float* efcW = (const float*)d_in[5];
    const float* efcb = (const float*)d_in[6];
    const float* dfcW = (const float*)d_in[7];
    const float* dfcb = (const float*)d_in[8];
    const float* dWih = (const float*)d_in[9];
    const float* dWhh = (const float*)d_in[10];
    const float* dbih = (const float*)d_in[11];
    const float* dbhh = (const float*)d_in[12];
    float* d_out = (float*)d_out_v;

    char* ws = (char*)d_ws;
    size_t off = 0;
    auto carve = [&](size_t bytes) {
        char* p = ws + off;
        off += (bytes + 255) & ~(size_t)255;
        return p;
    };

    const size_t xf_b  = (size_t)B_ * T_ * I_ * 2;
    const size_t hbE_b = (size_t)(T_ + 1) * ENC_STEP * 2;   // 129 unique slots
    const size_t hbD_b = (size_t)(T_ + 1) * DEC_STEP * 2;
    const size_t ce_b  = (size_t)B_ * H_ * 4;
    const size_t fxb_b = (size_t)B_ * 4 * I_ * 4;
    const size_t d1_b  = (size_t)B_ * H_ * 4;
    const size_t need_primary = xf_b + hbE_b + hbD_b + ce_b + fxb_b + d1_b + 4096;

    float* embd = d_out + (size_t)B_ * T_ * I_;

    if (ws_size == 0 || ws_size >= need_primary) {
        // ---------- primary: dataflow (sentinel) protocol ----------
        _Float16* xf     = (_Float16*)carve(xf_b);
        _Float16* hbufE  = (_Float16*)carve(hbE_b);
        _Float16* hbufD  = (_Float16*)carve(hbD_b);
        float*    c_e    = (float*)carve(ce_b);
        float*    fixedb = (float*)carve(fxb_b);
        float*    dec1   = (float*)carve(d1_b);

        // slot 0 = h0 = 0 (zero is valid data); slots 1..T poisoned with fp16 NaN
        hipMemsetAsync(hbufE, 0, (size_t)ENC_STEP * 2, stream);
        hipMemsetAsync((char*)hbufE + (size_t)ENC_STEP * 2, 0x7C, (size_t)T_ * ENC_STEP * 2, stream);
        hipMemsetAsync(hbufD, 0, (size_t)DEC_STEP * 2, stream);
        hipMemsetAsync((char*)hbufD + (size_t)DEC_STEP * 2, 0x7C, (size_t)T_ * DEC_STEP * 2, stream);

        shuffle_x_kernel<<<dim3(8192), 256, 0, stream>>>(x, xf);
        enc_df<<<dim3(256), 256, 0, stream>>>(xf, eWih, eWhh, ebih, ebhh, hbufE, c_e);
        small_gemm_kernel<<<dim3(E_ / 32, B_ / 32), 256, 0, stream>>>(
            c_e, H_, efcW, H_, efcb, nullptr, embd, E_, H_, 1);
        small_gemm_kernel<<<dim3(H_ / 32, B_ / 32), 256, 0, stream>>>(
            embd, E_, dfcW, E_, dfcb, nullptr, dec1, H_, E_, 1);
        small_gemm_kernel<<<dim3(4 * I_ / 32, B_ / 32), 256, 0, stream>>>(
            dec1, H_, dWih, H_ + I_, dbih, dbhh, fixedb, 4 * I_, H_, 0);
        dec_persist; // (symbol reference no-op avoided below)
        dec_df<<<dim3(256), 256, 0, stream>>>(dWih, dWhh, fixedb, hbufD, d_out);
    } else {
        // ---------- fallback: round-2 flag protocol ----------
        _Float16* xf     = (_Float16*)carve(xf_b);
        _Float16* hbufE  = (_Float16*)carve((size_t)2 * 262144 * 2);
        _Float16* hbufD  = (_Float16*)carve((size_t)2 * 131072 * 2);
        float*    c_e    = (float*)carve(ce_b);
        float*    fixedb = (float*)carve(fxb_b);
        float*    dec1   = (float*)carve(d1_b);
        int*      flagsE = (int*)carve(256 * 4);
        int*      flagsD = (int*)carve(256 * 4);

        hipMemsetAsync(flagsE, 0, 256 * 4, stream);
        hipMemsetAsync(flagsD, 0, 256 * 4, stream);
        hipMemsetAsync(hbufE, 0, (size_t)262144 * 2, stream);
        hipMemsetAsync(hbufD, 0, (size_t)131072 * 2, stream);

        shuffle_x_kernel<<<dim3(8192), 256, 0, stream>>>(x, xf);
        enc_persist<<<dim3(256), 256, 0, stream>>>(xf, eWih, eWhh, ebih, ebhh,
                                                   hbufE, c_e, flagsE);
        small_gemm_kernel<<<dim3(E_ / 32, B_ / 32), 256, 0, stream>>>(
            c_e, H_, efcW, H_, efcb, nullptr, embd, E_, H_, 1);
        small_gemm_kernel<<<dim3(H_ / 32, B_ / 32), 256, 0, stream>>>(
            embd, E_, dfcW, E_, dfcb, nullptr, dec1, H_, E_, 1);
        small_gemm_kernel<<<dim3(4 * I_ / 32, B_ / 32), 256, 0, stream>>>(
            dec1, H_, dWih, H_ + I_, dbih, dbhh, fixedb, 4 * I_, H_, 0);
        dec_persist<<<dim3(256), 256, 0, stream>>>(dWih, dWhh, fixedb,
                                                   hbufD, d_out, flagsD);
    }
}

// Round 2
// 1653.469 us; speedup vs baseline: 1.1193x; 1.0759x over previous
//
#include <hip/hip_runtime.h>
#include <hip/hip_fp16.h>

// LSTM Autoencoder: B=256, T=128, I=512, H=1024, E=256
// Round-4 HYBRID (per round-3 post-mortem):
//  - ENCODER: flag protocol (load h exactly ONCE, spin on flags only --
//    sentinel spin re-loads hammered the contended coherent-load fabric and
//    regressed 882->1008). Two tweaks: (a) barrier-free flag publication via
//    per-wave atomicAdd after per-wave vmcnt(0) drain; (b) x-MFMAs split
//    around the h-load issue so the first h group's LLC RT is covered.
//  - DECODER: dataflow sentinel protocol (measured ~200us faster than flags;
//    byte-identical to round-3 dec_df).

#define B_ 256
#define T_ 128
#define I_ 512
#define H_ 1024
#define E_ 256

#define ENC_STEP 262144   // fp16 elems per encoder h slot (256x1024)
#define DEC_STEP 131072   // fp16 elems per decoder h slot (256x512)
#define SENT32 0x7C7C7C7Cu   // two fp16 NaNs; unreachable by real h pairs

typedef _Float16 half8 __attribute__((ext_vector_type(8)));
typedef float floatx4 __attribute__((ext_vector_type(4)));

__device__ __forceinline__ float sigmoidf_(float x) { return 1.0f / (1.0f + __expf(-x)); }
__device__ __forceinline__ float tanhf_(float x) {
    x = fminf(fmaxf(x, -15.0f), 15.0f);
    float e = __expf(2.0f * x);
    return (e - 1.0f) / (e + 1.0f);
}

union HU { unsigned long long u[2]; half8 h; };

// coherent 16B load as 2x u64 relaxed-agent atomics (global_load_dwordx2 sc0 sc1)
__device__ __forceinline__ void ld_chunk(const _Float16* p, HU& v) {
    const unsigned long long* q = (const unsigned long long*)p;
    v.u[0] = __hip_atomic_load(q,     __ATOMIC_RELAXED, __HIP_MEMORY_SCOPE_AGENT);
    v.u[1] = __hip_atomic_load(q + 1, __ATOMIC_RELAXED, __HIP_MEMORY_SCOPE_AGENT);
}
__device__ __forceinline__ int chunk_ok(const HU& v) {
    unsigned a = (unsigned)v.u[0], b = (unsigned)(v.u[0] >> 32);
    unsigned c = (unsigned)v.u[1], d = (unsigned)(v.u[1] >> 32);
    return (int)((a != SENT32) & (b != SENT32) & (c != SENT32) & (d != SENT32));
}
template <int STRIDE>
__device__ __forceinline__ void load_grp(const _Float16* base, HU v[4]) {
#pragma unroll
    for (int m = 0; m < 4; ++m) ld_chunk(base + (size_t)m * STRIDE, v[m]);
}
template <int STRIDE>
__device__ __forceinline__ void fix_grp(const _Float16* base, HU v[4]) {
    while (!(chunk_ok(v[0]) & chunk_ok(v[1]) & chunk_ok(v[2]) & chunk_ok(v[3]))) {
        __builtin_amdgcn_s_sleep(1);
        load_grp<STRIDE>(base, v);
    }
}

__device__ __forceinline__ half8 ldg_h8_sc1(const _Float16* p) {
    HU v; ld_chunk(p, v); return v.h;
}
__device__ __forceinline__ void stg_h2_sc1(_Float16* p, float a, float b) {
    union { _Float16 h[2]; unsigned int u; } v;
    v.h[0] = (_Float16)a; v.h[1] = (_Float16)b;
    __hip_atomic_store((unsigned int*)p, v.u, __ATOMIC_RELAXED, __HIP_MEMORY_SCOPE_AGENT);
}
__device__ __forceinline__ void wait_vm0() {
    asm volatile("s_waitcnt vmcnt(0)" ::: "memory");
}
__device__ __forceinline__ void poll_rg(int* flags, int rgbase, int lane, int target) {
    while (__hip_atomic_load(&flags[rgbase + lane], __ATOMIC_RELAXED, __HIP_MEMORY_SCOPE_AGENT) < target)
        __builtin_amdgcn_s_sleep(1);
    asm volatile("" ::: "memory");
}

// ---------------- x -> MFMA A-fragment layout (once) ----------------
__global__ void shuffle_x_kernel(const float* __restrict__ x, _Float16* __restrict__ xf) {
    const int gg   = blockIdx.x * 256 + threadIdx.x;
    const int tile = gg >> 6;
    const int lane = gg & 63;
    const int t  = tile >> 8;
    const int rt = (tile >> 4) & 15;
    const int kc = tile & 15;
    const int b  = rt * 16 + (lane & 15);
    const int j0 = kc * 32 + ((lane >> 4) << 3);
    const float* src = x + ((size_t)b * T_ + t) * I_ + j0;
    float4 f0 = *(const float4*)src;
    float4 f1 = *(const float4*)(src + 4);
    half8 h = { (_Float16)f0.x, (_Float16)f0.y, (_Float16)f0.z, (_Float16)f0.w,
                (_Float16)f1.x, (_Float16)f1.y, (_Float16)f1.z, (_Float16)f1.w };
    *(half8*)(xf + (size_t)tile * 512 + lane * 8) = h;
}

// ---------------- small fp32 GEMM ----------------
__global__ __launch_bounds__(256) void small_gemm_kernel(
    const float* __restrict__ A, int lda,
    const float* __restrict__ W, int ldw,
    const float* __restrict__ b1, const float* __restrict__ b2,
    float* __restrict__ out, int N, int K, int relu)
{
    __shared__ float sA2[32][33];
    __shared__ float sW2[32][33];
    int tid = threadIdx.x;
    int tx = tid & 15, ty = tid >> 4;
    int m0 = blockIdx.y * 32, n0 = blockIdx.x * 32;
    float acc[2][2] = {};
    for (int k0 = 0; k0 < K; k0 += 32) {
        __syncthreads();
#pragma unroll
        for (int i = 0; i < 4; ++i) {
            int e = tid + i * 256;
            int r = e >> 5, c = e & 31;
            sA2[r][c] = A[(size_t)(m0 + r) * lda + k0 + c];
            sW2[r][c] = W[(size_t)(n0 + r) * ldw + k0 + c];
        }
        __syncthreads();
#pragma unroll
        for (int k = 0; k < 32; ++k) {
            float a0 = sA2[ty * 2][k], a1 = sA2[ty * 2 + 1][k];
            float w0 = sW2[tx * 2][k], w1 = sW2[tx * 2 + 1][k];
            acc[0][0] += a0 * w0; acc[0][1] += a0 * w1;
            acc[1][0] += a1 * w0; acc[1][1] += a1 * w1;
        }
    }
#pragma unroll
    for (int i = 0; i < 2; ++i)
#pragma unroll
        for (int j = 0; j < 2; ++j) {
            int m = m0 + ty * 2 + i, n = n0 + tx * 2 + j;
            float v = acc[i][j] + b1[n] + (b2 ? b2[n] : 0.0f);
            if (relu) v = fmaxf(v, 0.0f);
            out[(size_t)m * N + n] = v;
        }
}

// ================= encoder: flag protocol, barrier-free publication =================
// grid 256 = 4 row-groups (64 batch rows) x 64 col-CUs (16 h-cols -> 64 gate-cols)
// flags[blk] counts completed wave-drains: block done with step s <=> flags[blk]==4*(s+1).
__global__ __launch_bounds__(256, 1) void enc_persist(
    const _Float16* __restrict__ xf,
    const float* __restrict__ Wih, const float* __restrict__ Whh,
    const float* __restrict__ bih, const float* __restrict__ bhh,
    _Float16* __restrict__ hbuf, float* __restrict__ c_out, int* __restrict__ flags)
{
    const int tid  = threadIdx.x;
    const int wave = tid >> 6, lane = tid & 63;
    const int q = lane >> 4, n15 = lane & 15;
    const int blk = blockIdx.x;
    const int rg = blk >> 6, cc = blk & 63;

    // weights -> VGPRs (192 regs/lane)
    half8 bw[4][12];
#pragma unroll
    for (int g = 0; g < 4; ++g) {
        const int jc = g * H_ + cc * 16 + n15;
#pragma unroll
        for (int kc = 0; kc < 12; ++kc) {
            const int k = (4 * kc + wave) * 32 + q * 8;
            const float* src = (k < I_) ? (Wih + (size_t)jc * I_ + k)
                                        : (Whh + (size_t)jc * H_ + (k - I_));
            float4 f0 = *(const float4*)src;
            float4 f1 = *(const float4*)(src + 4);
            bw[g][kc] = half8{(_Float16)f0.x, (_Float16)f0.y, (_Float16)f0.z, (_Float16)f0.w,
                              (_Float16)f1.x, (_Float16)f1.y, (_Float16)f1.z, (_Float16)f1.w};
        }
    }

    const int hcp = tid & 7;    // owned col-pair (2*hcp, 2*hcp+1)
    const int rT  = tid >> 3;   // owned row (phase A: rT, phase B: 32+rT)
    float breg[4][2];
#pragma unroll
    for (int g = 0; g < 4; ++g)
#pragma unroll
        for (int e = 0; e < 2; ++e) {
            const int j = g * H_ + cc * 16 + 2 * hcp + e;
            breg[g][e] = bih[j] + bhh[j];
        }
    float creg[2][2] = {{0.f, 0.f}, {0.f, 0.f}};

    __shared__ float preT[4][64][35];
    const size_t laneoff = (size_t)lane * 8;

    for (int s = 0; s < T_; ++s) {
        const _Float16* __restrict__ hcur = hbuf + (size_t)(s & 1) * 262144;
        _Float16* __restrict__ hnxt = hbuf + (size_t)((s + 1) & 1) * 262144;

        floatx4 acc[4][4];
#pragma unroll
        for (int m = 0; m < 4; ++m)
#pragma unroll
            for (int n = 0; n < 4; ++n) acc[m][n] = floatx4{0.f, 0.f, 0.f, 0.f};

        // ---- x loads + first half of x-MFMAs (hides producer lag)
        half8 X[4][4];
#pragma unroll
        for (int kc = 0; kc < 4; ++kc)
#pragma unroll
            for (int m = 0; m < 4; ++m)
                X[kc][m] = *(const half8*)(xf + (((size_t)s * 16 + rg * 4 + m) * 16
                                                + (4 * kc + wave)) * 512 + laneoff);
#pragma unroll
        for (int kc = 0; kc < 2; ++kc)
#pragma unroll
            for (int n = 0; n < 4; ++n)
#pragma unroll
                for (int m = 0; m < 4; ++m)
                    acc[m][n] = __builtin_amdgcn_mfma_f32_16x16x32_f16(
                        X[kc][m], bw[n][kc], acc[m][n], 0, 0, 0);

        // ---- wait for h_s: all 64 blocks of rg have all 4 waves drained
        poll_rg(flags, rg * 64, lane, 4 * s);

        // ---- issue first 4 h-load groups immediately after the poll
        half8 Hb[4][4];
#pragma unroll
        for (int kc = 4; kc < 8; ++kc)
#pragma unroll
            for (int m = 0; m < 4; ++m)
                Hb[kc - 4][m] = ldg_h8_sc1(hcur + ((size_t)(rg * 4 + m) * 32
                                                   + (4 * kc + wave - 16)) * 512 + laneoff);

        // ---- second half of x-MFMAs covers the first h group's LLC RT
#pragma unroll
        for (int kc = 2; kc < 4; ++kc)
#pragma unroll
            for (int n = 0; n < 4; ++n)
#pragma unroll
                for (int m = 0; m < 4; ++m)
                    acc[m][n] = __builtin_amdgcn_mfma_f32_16x16x32_f16(
                        X[kc][m], bw[n][kc], acc[m][n], 0, 0, 0);

        // ---- h phase: depth-4 pipelined sc1 loads + 128 MFMAs
#pragma unroll
        for (int kc = 4; kc < 12; ++kc) {
            const int sl = kc & 3;
#pragma unroll
            for (int n = 0; n < 4; ++n)
#pragma unroll
                for (int m = 0; m < 4; ++m)
                    acc[m][n] = __builtin_amdgcn_mfma_f32_16x16x32_f16(
                        Hb[sl][m], bw[n][kc], acc[m][n], 0, 0, 0);
            if (kc < 8) {
#pragma unroll
                for (int m = 0; m < 4; ++m)
                    Hb[sl][m] = ldg_h8_sc1(hcur + ((size_t)(rg * 4 + m) * 32
                                                   + (4 * (kc + 4) + wave - 16)) * 512 + laneoff);
            }
        }

        // ---- epilogue: 2 phases (rows 0..31, 32..63)
#pragma unroll
        for (int p = 0; p < 2; ++p) {
            if (p) __syncthreads();   // phase-A reads done before phase-B writes
#pragma unroll
            for (int m = 0; m < 2; ++m)
#pragma unroll
                for (int n = 0; n < 4; ++n)
#pragma unroll
                    for (int r = 0; r < 4; ++r)
                        preT[wave][n * 16 + n15][m * 16 + q * 4 + r] = acc[p * 2 + m][n][r];
            __syncthreads();
            float pg[4][2];
#pragma unroll
            for (int g = 0; g < 4; ++g)
#pragma unroll
                for (int e = 0; e < 2; ++e) {
                    const int col = g * 16 + 2 * hcp + e;
                    pg[g][e] = preT[0][col][rT] + preT[1][col][rT]
                             + preT[2][col][rT] + preT[3][col][rT] + breg[g][e];
                }
            float hv[2];
#pragma unroll
            for (int e = 0; e < 2; ++e) {
                const float ig = sigmoidf_(pg[0][e]);
                const float fg = sigmoidf_(pg[1][e]);
                const float gg = tanhf_(pg[2][e]);
                const float og = sigmoidf_(pg[3][e]);
                const float c  = fg * creg[p][e] + ig * gg;
                creg[p][e] = c;
                hv[e] = og * tanhf_(c);
            }
            const int row = p * 32 + rT;
            const int j   = cc * 16 + 2 * hcp;
            const int kch = j >> 5, j5 = j & 31;
            const int lt  = (row & 15) | ((j5 >> 3) << 4);
            stg_h2_sc1(hnxt + ((size_t)(rg * 4 + (row >> 4)) * 32 + kch) * 512
                            + lt * 8 + (j5 & 7), hv[0], hv[1]);
        }

        // ---- barrier-free publication: each wave drains its own stores,
        //      lane 0 bumps the block counter. Count==4 <=> all waves drained.
        wait_vm0();
        if (lane == 0)
            __hip_atomic_fetch_add(&flags[blk], 1, __ATOMIC_RELAXED, __HIP_MEMORY_SCOPE_AGENT);
        __syncthreads();     // preT reuse protection only (off the inter-block path)
    }

    // final cell state (plain stores; visible via kernel-end release)
#pragma unroll
    for (int p = 0; p < 2; ++p)
        *(float2*)(c_out + (size_t)(rg * 64 + p * 32 + rT) * H_ + cc * 16 + 2 * hcp)
            = float2{creg[p][0], creg[p][1]};
}

// ================= decoder: dataflow sentinel protocol (round-3, measured) =================
__global__ __launch_bounds__(256, 1) void dec_df(
    const float* __restrict__ dWih, const float* __restrict__ dWhh,
    const float* __restrict__ fixedb,
    _Float16* __restrict__ hbuf, float* __restrict__ out)
{
    const int tid  = threadIdx.x;
    const int wave = tid >> 6, lane = tid & 63;
    const int q = lane >> 4, n15 = lane & 15;
    const int blk = blockIdx.x;
    const int rg = blk >> 6, cc = blk & 63;

    half8 bw[2][4];
#pragma unroll
    for (int n = 0; n < 2; ++n) {
        const int jc = (n * 2 + (n15 >> 3)) * I_ + cc * 8 + (n15 & 7);
#pragma unroll
        for (int kc = 0; kc < 4; ++kc) {
            const int k = wave * 128 + kc * 32 + q * 8;
            const float* s0 = dWih + (size_t)jc * (H_ + I_) + H_ + k;
            const float* s1 = dWhh + (size_t)jc * I_ + k;
            float4 a0 = *(const float4*)s0, a1 = *(const float4*)(s0 + 4);
            float4 b0 = *(const float4*)s1, b1 = *(const float4*)(s1 + 4);
            bw[n][kc] = half8{(_Float16)(a0.x + b0.x), (_Float16)(a0.y + b0.y),
                              (_Float16)(a0.z + b0.z), (_Float16)(a0.w + b0.w),
                              (_Float16)(a1.x + b1.x), (_Float16)(a1.y + b1.y),
                              (_Float16)(a1.z + b1.z), (_Float16)(a1.w + b1.w)};
        }
    }

    const int hcp = tid & 3;
    const int rT  = tid >> 2;
    const int brow = rg * 64 + rT;
    float fx[4][2];
#pragma unroll
    for (int g = 0; g < 4; ++g)
#pragma unroll
        for (int e = 0; e < 2; ++e)
            fx[g][e] = fixedb[(size_t)brow * (4 * I_) + g * I_ + cc * 8 + 2 * hcp + e];
    float creg2[2] = {0.f, 0.f};

    __shared__ float preT[4][32][67];
    const size_t laneoff = (size_t)lane * 8;

    for (int s = 0; s < T_; ++s) {
        const _Float16* __restrict__ hcur = hbuf + (size_t)s * DEC_STEP;
        _Float16* __restrict__ hnxt = hbuf + (size_t)(s + 1) * DEC_STEP;

        HU Hb[4][4];
#pragma unroll
        for (int kc = 0; kc < 4; ++kc)
            load_grp<16 * 512>(hcur + ((size_t)(rg * 4) * 16 + (wave * 4 + kc)) * 512
                                    + laneoff, Hb[kc]);

        floatx4 acc[4][2];
#pragma unroll
        for (int m = 0; m < 4; ++m)
#pragma unroll
            for (int n = 0; n < 2; ++n) acc[m][n] = floatx4{0.f, 0.f, 0.f, 0.f};
#pragma unroll
        for (int kc = 0; kc < 4; ++kc) {
            fix_grp<16 * 512>(hcur + ((size_t)(rg * 4) * 16 + (wave * 4 + kc)) * 512
                                   + laneoff, Hb[kc]);
#pragma unroll
            for (int n = 0; n < 2; ++n)
#pragma unroll
                for (int m = 0; m < 4; ++m)
                    acc[m][n] = __builtin_amdgcn_mfma_f32_16x16x32_f16(
                        Hb[kc][m].h, bw[n][kc], acc[m][n], 0, 0, 0);
        }

#pragma unroll
        for (int p = 0; p < 2; ++p) {
            if (p) __syncthreads();
#pragma unroll
            for (int m = 0; m < 2; ++m)
#pragma unroll
                for (int n = 0; n < 2; ++n)
#pragma unroll
                    for (int r = 0; r < 4; ++r)
                        preT[wave][n * 16 + n15][m * 16 + q * 4 + r] = acc[p * 2 + m][n][r];
            __syncthreads();
            if ((rT >> 5) == p) {
                const int rl = rT & 31;
                float pg[4][2];
#pragma unroll
                for (int g = 0; g < 4; ++g)
#pragma unroll
                    for (int e = 0; e < 2; ++e) {
                        const int col = (g >> 1) * 16 + (g & 1) * 8 + 2 * hcp + e;
                        pg[g][e] = preT[0][col][rl] + preT[1][col][rl]
                                 + preT[2][col][rl] + preT[3][col][rl] + fx[g][e];
                    }
                float hv[2];
#pragma unroll
                for (int e = 0; e < 2; ++e) {
                    const float ig = sigmoidf_(pg[0][e]);
                    const float fg = sigmoidf_(pg[1][e]);
                    const float gg = tanhf_(pg[2][e]);
                    const float og = sigmoidf_(pg[3][e]);
                    const float c  = fg * creg2[e] + ig * gg;
                    creg2[e] = c;
                    hv[e] = og * tanhf_(c);
                }
                *(float2*)(out + ((size_t)brow * T_ + (T_ - 1 - s)) * I_ + cc * 8 + 2 * hcp)
                    = float2{hv[0], hv[1]};
                const int j = cc * 8 + 2 * hcp;
                const int kch = j >> 5, j5 = j & 31;
                const int lt  = (rT & 15) | ((j5 >> 3) << 4);
                stg_h2_sc1(hnxt + ((size_t)(rg * 4 + (rT >> 4)) * 16 + kch) * 512
                                + lt * 8 + (j5 & 7), hv[0], hv[1]);
            }
        }
        __syncthreads();
    }
}

// ================= FALLBACK decoder (flag protocol) for tiny workspaces =================
__global__ __launch_bounds__(256, 1) void dec_persist(
    const float* __restrict__ dWih, const float* __restrict__ dWhh,
    const float* __restrict__ fixedb,
    _Float16* __restrict__ hbuf, float* __restrict__ out, int* __restrict__ flags)
{
    const int tid  = threadIdx.x;
    const int wave = tid >> 6, lane = tid & 63;
    const int q = lane >> 4, n15 = lane & 15;
    const int blk = blockIdx.x;
    const int rg = blk >> 6, cc = blk & 63;

    half8 bw[2][4];
#pragma unroll
    for (int n = 0; n < 2; ++n) {
        const int jc = (n * 2 + (n15 >> 3)) * I_ + cc * 8 + (n15 & 7);
#pragma unroll
        for (int kc = 0; kc < 4; ++kc) {
            const int k = wave * 128 + kc * 32 + q * 8;
            const float* s0 = dWih + (size_t)jc * (H_ + I_) + H_ + k;
            const float* s1 = dWhh + (size_t)jc * I_ + k;
            float4 a0 = *(const float4*)s0, a1 = *(const float4*)(s0 + 4);
            float4 b0 = *(const float4*)s1, b1 = *(const float4*)(s1 + 4);
            bw[n][kc] = half8{(_Float16)(a0.x + b0.x), (_Float16)(a0.y + b0.y),
                              (_Float16)(a0.z + b0.z), (_Float16)(a0.w + b0.w),
                              (_Float16)(a1.x + b1.x), (_Float16)(a1.y + b1.y),
                              (_Float16)(a1.z + b1.z), (_Float16)(a1.w + b1.w)};
        }
    }

    const int hcp = tid & 3;
    const int rT  = tid >> 2;
    const int brow = rg * 64 + rT;
    float fx[4][2];
#pragma unroll
    for (int g = 0; g < 4; ++g)
#pragma unroll
        for (int e = 0; e < 2; ++e)
            fx[g][e] = fixedb[(size_t)brow * (4 * I_) + g * I_ + cc * 8 + 2 * hcp + e];
    float creg2[2] = {0.f, 0.f};

    __shared__ float preT[4][32][67];
    const size_t laneoff = (size_t)lane * 8;

    for (int s = 0; s < T_; ++s) {
        const _Float16* __restrict__ hcur = hbuf + (size_t)(s & 1) * 131072;
        _Float16* __restrict__ hnxt = hbuf + (size_t)((s + 1) & 1) * 131072;

        poll_rg(flags, rg * 64, lane, s);

        half8 Hb[4][4];
#pragma unroll
        for (int kc = 0; kc < 4; ++kc)
#pragma unroll
            for (int m = 0; m < 4; ++m)
                Hb[kc][m] = ldg_h8_sc1(hcur + ((size_t)(rg * 4 + m) * 16
                                               + (wave * 4 + kc)) * 512 + laneoff);
        floatx4 acc[4][2];
#pragma unroll
        for (int m = 0; m < 4; ++m)
#pragma unroll
            for (int n = 0; n < 2; ++n) acc[m][n] = floatx4{0.f, 0.f, 0.f, 0.f};
#pragma unroll
        for (int kc = 0; kc < 4; ++kc)
#pragma unroll
            for (int n = 0; n < 2; ++n)
#pragma unroll
                for (int m = 0; m < 4; ++m)
                    acc[m][n] = __builtin_amdgcn_mfma_f32_16x16x32_f16(
                        Hb[kc][m], bw[n][kc], acc[m][n], 0, 0, 0);

#pragma unroll
        for (int p = 0; p < 2; ++p) {
            if (p) __syncthreads();
#pragma unroll
            for (int m = 0; m < 2; ++m)
#pragma unroll
                for (int n = 0; n < 2; ++n)
#pragma unroll
                    for (int r = 0; r < 4; ++r)
                        preT[wave][n * 16 + n15][m * 16 + q * 4 + r] = acc[p * 2 + m][n][r];
            __syncthreads();
            if ((rT >> 5) == p) {
                const int rl = rT & 31;
                float pg[4][2];
#pragma unroll
                for (int g = 0; g < 4; ++g)
#pragma unroll
                    for (int e = 0; e < 2; ++e) {
                        const int col = (g >> 1) * 16 + (g & 1) * 8 + 2 * hcp + e;
                        pg[g][e] = preT[0][col][rl] + preT[1][col][rl]
                                 + preT[2][col][rl] + preT[3][col][rl] + fx[g][e];
                    }
                float hv[2];
#pragma unroll
                for (int e = 0; e < 2; ++e) {
                    const float ig = sigmoidf_(pg[0][e]);
                    const float fg = sigmoidf_(pg[1][e]);
                    const float gg = tanhf_(pg[2][e]);
                    const float og = sigmoidf_(pg[3][e]);
                    const float c  = fg * creg2[e] + ig * gg;
                    creg2[e] = c;
                    hv[e] = og * tanhf_(c);
                }
                *(float2*)(out + ((size_t)brow * T_ + (T_ - 1 - s)) * I_ + cc * 8 + 2 * hcp)
                    = float2{hv[0], hv[1]};
                const int j = cc * 8 + 2 * hcp;
                const int kch = j >> 5, j5 = j & 31;
                const int lt  = (rT & 15) | ((j5 >> 3) << 4);
                stg_h2_sc1(hnxt + ((size_t)(rg * 4 + (rT >> 4)) * 16 + kch) * 512
                                + lt * 8 + (j5 & 7), hv[0], hv[1]);
            }
        }

        wait_vm0();
        __syncthreads();
        if (tid == 0)
            __hip_atomic_store(&flags[blk], s + 1, __ATOMIC_RELAXED, __HIP_MEMORY_SCOPE_AGENT);
    }
}

// ---------------- launch ----------------
extern "C" void kernel_launch(void* const* d_in, const int* in_sizes, int n_in,
                              void* d_out_v, int out_size, void* d_ws, size_t ws_size,
                              hipStream_t stream) {
    (void)in_sizes; (void)n_in; (void)out_size;
    const float* x    = (const float*)d_in[0];
    const float* eWih = (const float*)d_in[1];
    const float* eWhh = (const float*)d_in[2];
    const float* ebih = (const float*)d_in[3];
    const float* ebhh = (const float*)d_in[4];
    const float* efcW = (const float*)d_in[5];
    const float* efcb = (const float*)d_in[6];
    const float* dfcW = (const float*)d_in[7];
    const float* dfcb = (const float*)d_in[8];
    const float* dWih = (const float*)d_in[9];
    const float* dWhh = (const float*)d_in[10];
    const float* dbih = (const float*)d_in[11];
    const float* dbhh = (const float*)d_in[12];
    float* d_out = (float*)d_out_v;

    char* ws = (char*)d_ws;
    size_t off = 0;
    auto carve = [&](size_t bytes) {
        char* p = ws + off;
        off += (bytes + 255) & ~(size_t)255;
        return p;
    };

    const size_t xf_b  = (size_t)B_ * T_ * I_ * 2;
    const size_t hbE_b = (size_t)2 * ENC_STEP * 2;          // 2-slot ring (flag protocol)
    const size_t hbD_b = (size_t)(T_ + 1) * DEC_STEP * 2;   // 129 unique slots (dataflow)
    const size_t ce_b  = (size_t)B_ * H_ * 4;
    const size_t fxb_b = (size_t)B_ * 4 * I_ * 4;
    const size_t d1_b  = (size_t)B_ * H_ * 4;
    const size_t need_primary = xf_b + hbE_b + hbD_b + ce_b + fxb_b + d1_b + 8192;

    float* embd = d_out + (size_t)B_ * T_ * I_;

    if (ws_size == 0 || ws_size >= need_primary) {
        // ---------- primary: flag encoder + dataflow decoder ----------
        _Float16* xf     = (_Float16*)carve(xf_b);
        _Float16* hbufE  = (_Float16*)carve(hbE_b);
        _Float16* hbufD  = (_Float16*)carve(hbD_b);
        float*    c_e    = (float*)carve(ce_b);
        float*    fixedb = (float*)carve(fxb_b);
        float*    dec1   = (float*)carve(d1_b);
        int*      flagsE = (int*)carve(256 * 4);

        hipMemsetAsync(flagsE, 0, 256 * 4, stream);
        hipMemsetAsync(hbufE, 0, (size_t)ENC_STEP * 2, stream);  // h0 = 0 (slot 0)
        // decoder: slot 0 = h0 = 0; slots 1..T poisoned with fp16 NaN
        hipMemsetAsync(hbufD, 0, (size_t)DEC_STEP * 2, stream);
        hipMemsetAsync((char*)hbufD + (size_t)DEC_STEP * 2, 0x7C, (size_t)T_ * DEC_STEP * 2, stream);

        shuffle_x_kernel<<<dim3(8192), 256, 0, stream>>>(x, xf);
        enc_persist<<<dim3(256), 256, 0, stream>>>(xf, eWih, eWhh, ebih, ebhh,
                                                   hbufE, c_e, flagsE);
        small_gemm_kernel<<<dim3(E_ / 32, B_ / 32), 256, 0, stream>>>(
            c_e, H_, efcW, H_, efcb, nullptr, embd, E_, H_, 1);
        small_gemm_kernel<<<dim3(H_ / 32, B_ / 32), 256, 0, stream>>>(
            embd, E_, dfcW, E_, dfcb, nullptr, dec1, H_, E_, 1);
        small_gemm_kernel<<<dim3(4 * I_ / 32, B_ / 32), 256, 0, stream>>>(
            dec1, H_, dWih, H_ + I_, dbih, dbhh, fixedb, 4 * I_, H_, 0);
        dec_df<<<dim3(256), 256, 0, stream>>>(dWih, dWhh, fixedb, hbufD, d_out);
    } else {
        // ---------- fallback: flag protocol both (2-slot rings, tiny ws) ----------
        _Float16* xf     = (_Float16*)carve(xf_b);
        _Float16* hbufE  = (_Float16*)carve((size_t)2 * ENC_STEP * 2);
        _Float16* hbufD  = (_Float16*)carve((size_t)2 * DEC_STEP * 2);
        float*    c_e    = (float*)carve(ce_b);
        float*    fixedb = (float*)carve(fxb_b);
        float*    dec1   = (float*)carve(d1_b);
        int*      flagsE = (int*)carve(256 * 4);
        int*      flagsD = (int*)carve(256 * 4);

        hipMemsetAsync(flagsE, 0, 256 * 4, stream);
        hipMemsetAsync(flagsD, 0, 256 * 4, stream);
        hipMemsetAsync(hbufE, 0, (size_t)ENC_STEP * 2, stream);
        hipMemsetAsync(hbufD, 0, (size_t)DEC_STEP * 2, stream);

        shuffle_x_kernel<<<dim3(8192), 256, 0, stream>>>(x, xf);
        enc_persist<<<dim3(256), 256, 0, stream>>>(xf, eWih, eWhh, ebih, ebhh,
                                                   hbufE, c_e, flagsE);
        small_gemm_kernel<<<dim3(E_ / 32, B_ / 32), 256, 0, stream>>>(
            c_e, H_, efcW, H_, efcb, nullptr, embd, E_, H_, 1);
        small_gemm_kernel<<<dim3(H_ / 32, B_ / 32), 256, 0, stream>>>(
            embd, E_, dfcW, E_, dfcb, nullptr, dec1, H_, E_, 1);
        small_gemm_kernel<<<dim3(4 * I_ / 32, B_ / 32), 256, 0, stream>>>(
            dec1, H_, dWih, H_ + I_, dbih, dbhh, fixedb, 4 * I_, H_, 0);
        dec_persist<<<dim3(256), 256, 0, stream>>>(dWih, dWhh, fixedb,
                                                   hbufD, d_out, flagsD);
    }
}